// Round 5
// baseline (971.651 us; speedup 1.0000x reference)
//
#include <hip/hip_runtime.h>
#include <hip/hip_bf16.h>
#include <stdint.h>

#define T_TOK 8192
#define D_DIM 1024
#define E_NUM 8
#define H_DIM 4096
#define WL_MAX 72

typedef short bf16x8 __attribute__((ext_vector_type(8)));
typedef float f32x4 __attribute__((ext_vector_type(4)));

#define AS1 __attribute__((address_space(1)))
#define AS3 __attribute__((address_space(3)))

__device__ __forceinline__ unsigned short f2b(float f) {
  union { float f; uint32_t u; } v; v.f = f;
  uint32_t r = (v.u + 0x7fffu + ((v.u >> 16) & 1u)) >> 16;
  return (unsigned short)r;
}

__device__ __forceinline__ float gelu_tanh(float x) {
  float u = 0.7978845608028654f * (x + 0.044715f * x * x * x);
  u = fminf(fmaxf(u, -15.f), 15.f);
  float e = __expf(2.f * u);
  float t = (e - 1.f) / (e + 1.f);
  return 0.5f * x * (1.f + t);
}

__device__ __forceinline__ void gload_lds16(const void* g, void* l) {
  __builtin_amdgcn_global_load_lds((const AS1 uint32_t*)g, (AS3 uint32_t*)l, 16, 0, 0);
}

// ---------------- gate + x->bf16 conversion fused ----------------
__global__ __launch_bounds__(256) void moe_gate_conv(const float* __restrict__ x,
                                                     const float* __restrict__ gw,
                                                     const float* __restrict__ gb,
                                                     unsigned short* __restrict__ xb,
                                                     int2* __restrict__ sel,
                                                     float2* __restrict__ wts,
                                                     int* __restrict__ meta) {
  int lane = threadIdx.x & 63;
  int t = blockIdx.x * 4 + (threadIdx.x >> 6);
  const float* xr = x + (size_t)t * D_DIM;
  unsigned short* xo = xb + (size_t)t * D_DIM;
  float acc[8];
#pragma unroll
  for (int e = 0; e < 8; e++) acc[e] = 0.f;
#pragma unroll
  for (int i = 0; i < 4; i++) {
    int d0 = lane * 4 + i * 256;
    float4 xv = *(const float4*)(xr + d0);
    ushort4 o;
    o.x = f2b(xv.x); o.y = f2b(xv.y); o.z = f2b(xv.z); o.w = f2b(xv.w);
    *(ushort4*)(xo + d0) = o;
    const float* gp = gw + (size_t)d0 * 8;
    float xs[4] = {xv.x, xv.y, xv.z, xv.w};
#pragma unroll
    for (int j = 0; j < 4; j++) {
#pragma unroll
      for (int e = 0; e < 8; e++) acc[e] += xs[j] * gp[j * 8 + e];
    }
  }
#pragma unroll
  for (int off = 32; off > 0; off >>= 1) {
#pragma unroll
    for (int e = 0; e < 8; e++) acc[e] += __shfl_xor(acc[e], off);
  }
  if (lane == 0) {
    float lg[8];
#pragma unroll
    for (int e = 0; e < 8; e++) lg[e] = acc[e] + gb[e];
    int e0 = 0; float b0 = lg[0];
#pragma unroll
    for (int e = 1; e < 8; e++) if (lg[e] > b0) { b0 = lg[e]; e0 = e; }
    int e1 = -1; float b1v = -1e30f;
#pragma unroll
    for (int e = 0; e < 8; e++) if (e != e0 && lg[e] > b1v) { b1v = lg[e]; e1 = e; }
    float d = __expf(b1v - b0);
    float w0 = 1.f / (1.f + d), w1 = d / (1.f + d);
    sel[t] = make_int2(e0, e1);
    wts[t] = make_float2(w0, w1);
    atomicAdd(&meta[e0], 1);
    atomicAdd(&meta[e1], 1);
  }
}

// ---------------- transpose + convert: in [E][R][C] f32 -> out [E][C][R] bf16 ----------------
__global__ __launch_bounds__(256) void moe_transpose(const float* __restrict__ in,
                                                     unsigned short* __restrict__ out,
                                                     int R, int C) {
  int e = blockIdx.z;
  int c0 = blockIdx.x * 64, r0 = blockIdx.y * 64;
  __shared__ float tile[64][65];
  const float* ine = in + (size_t)e * R * C;
  unsigned short* oute = out + (size_t)e * R * C;
  int tr = threadIdx.x >> 2;
  int tc4 = (threadIdx.x & 3) * 16;
#pragma unroll
  for (int p = 0; p < 4; p++) {
    int c = tc4 + p * 4;
    float4 v = *(const float4*)(ine + (size_t)(r0 + tr) * C + c0 + c);
    tile[tr][c] = v.x; tile[tr][c + 1] = v.y; tile[tr][c + 2] = v.z; tile[tr][c + 3] = v.w;
  }
  __syncthreads();
#pragma unroll
  for (int p = 0; p < 4; p++) {
    int rr = tc4 + p * 4;
    ushort4 o;
    o.x = f2b(tile[rr + 0][tr]);
    o.y = f2b(tile[rr + 1][tr]);
    o.z = f2b(tile[rr + 2][tr]);
    o.w = f2b(tile[rr + 3][tr]);
    *(ushort4*)(oute + (size_t)(c0 + tr) * R + r0 + rr) = o;
  }
}

// meta layout: [0..7] counts, [8..16] offsets(+total), [17] wl_count, [20..27] cursor
__global__ void moe_scan(int* meta, int2* wl) {
  if (threadIdx.x == 0 && blockIdx.x == 0) {
    int o = 0;
    for (int e = 0; e < 8; e++) { meta[8 + e] = o; meta[20 + e] = o; o += meta[e]; }
    meta[16] = o;
    int w = 0;
    for (int e = 0; e < 8; e++)
      for (int m0 = 0; m0 < meta[e]; m0 += 256) wl[w++] = make_int2(e, m0);
    meta[17] = w;
  }
}

__global__ __launch_bounds__(256) void moe_scatter(const int2* __restrict__ sel,
                                                   const float2* __restrict__ wts,
                                                   int* __restrict__ meta,
                                                   int* __restrict__ token_id,
                                                   float* __restrict__ weightv) {
  int t = blockIdx.x * 256 + threadIdx.x;
  if (t >= T_TOK) return;
  int2 s = sel[t];
  float2 w = wts[t];
  int p0 = atomicAdd(&meta[20 + s.x], 1); token_id[p0] = t; weightv[p0] = w.x;
  int p1 = atomicAdd(&meta[20 + s.y], 1); token_id[p1] = t; weightv[p1] = w.y;
}

// ---------------- out init: out[t] = w0*b2[e0] + w1*b2[e1] ----------------
__global__ __launch_bounds__(256) void moe_outinit(const int2* __restrict__ sel,
                                                   const float2* __restrict__ wts,
                                                   const float* __restrict__ b2,
                                                   float* __restrict__ out) {
  int t = blockIdx.x;
  int d = threadIdx.x * 4;
  int2 s = sel[t];
  float2 w = wts[t];
  float4 a = *(const float4*)(b2 + (size_t)s.x * D_DIM + d);
  float4 b = *(const float4*)(b2 + (size_t)s.y * D_DIM + d);
  float4 o;
  o.x = w.x * a.x + w.y * b.x;
  o.y = w.x * a.y + w.y * b.y;
  o.z = w.x * a.z + w.y * b.z;
  o.w = w.x * a.w + w.y * b.w;
  *(float4*)(out + (size_t)t * D_DIM + d) = o;
}

// ---------------- pipelined grouped GEMM, BM=BN=256, BK=32, 512 thr ----------------
// 3 LDS buffers, 2-deep prefetch, counted vmcnt(4), ONE barrier per K-tile,
// XOR-swizzled LDS layout (pre-swizzled global source + swizzled ds_read offset).
// MODE 0: h[p] = gelu(x[tok[p]] @ w1[e] + b1[e])                 grid (16, WL)
// MODE 1: out[tok[p]] += weight[p] * (h[p] @ w2[e])[k-half]      grid (8, WL), atomic f32
template<int MODE>
__global__ __launch_bounds__(512, 2) void moe_gemm_pipe(
    const unsigned short* __restrict__ Amat,
    const unsigned short* __restrict__ Bmat,
    const float* __restrict__ bias,
    const int* __restrict__ meta,
    const int2* __restrict__ wl,
    const int* __restrict__ token_id,
    const float* __restrict__ weightv,
    unsigned short* __restrict__ hout,
    float* __restrict__ yout) {
  constexpr int KLEN = MODE ? 4096 : 1024;   // A/B row length (elements)
  constexpr int NK   = MODE ? 64 : 32;       // K-tiles of 32 (MODE1: per K-half)

  int wi = blockIdx.y;
  if (wi >= meta[17]) return;
  int e = wl[wi].x, m0 = wl[wi].y;
  int seg = meta[8 + e], ne = meta[9 + e] - seg;
  int n0, kbase;
  if (MODE) { n0 = (int)(blockIdx.x >> 1) * 256; kbase = (int)(blockIdx.x & 1) * 2048; }
  else      { n0 = blockIdx.x * 256; kbase = 0; }

  __shared__ unsigned short As[3][8192];   // 16 KiB each: 256 rows x 32 k (64B rows), swizzled
  __shared__ unsigned short Bs[3][8192];

  int tid = threadIdx.x, lane = tid & 63, w = tid >> 6;  // 8 waves
  int wm = w >> 2, wn = w & 3;                           // 2M x 4N wave grid

  // Swizzle: physical chunk P = B ^ ((B>>2)&7)  (16B chunks; B = logical = row*4 + col16).
  // Staging writes LDS linearly (slot = lane), so lane must fetch logical chunk binv(lane).
  int binv = (lane & 0x38) | ((lane ^ (lane >> 2)) & 6) | ((lane ^ (lane >> 2) ^ (lane >> 4)) & 1);

  const unsigned short* aSrc[2];
  const unsigned short* bSrc[2];
#pragma unroll
  for (int q = 0; q < 2; ++q) {
    int lchunk = ((w * 2 + q) << 6) | binv;
    int row = lchunk >> 2;
    int ko = (lchunk & 3) * 8;
    int gi = m0 + row; if (gi >= ne) gi = m0;
    if (MODE) aSrc[q] = Amat + (size_t)(seg + gi) * KLEN + kbase + ko;
    else      aSrc[q] = Amat + (size_t)token_id[seg + gi] * KLEN + ko;
    bSrc[q] = Bmat + (size_t)e * (4096 * 1024) + (size_t)(n0 + row) * KLEN + kbase + ko;
  }

  auto STAGE = [&](int buf, int kt) {
#pragma unroll
    for (int q = 0; q < 2; ++q) {
      gload_lds16(aSrc[q] + kt * 32, &As[buf][(w * 2 + q) * 512]);
      gload_lds16(bSrc[q] + kt * 32, &Bs[buf][(w * 2 + q) * 512]);
    }
  };

  f32x4 acc[8][4] = {};
  // fragment read offsets (elements), XOR-swizzled; row&7 == lane&7 for all mf/nf
  const int aoff = (((wm * 128 + (lane & 15)) * 32 + (lane >> 4) * 8)) ^ ((lane & 7) << 3);
  const int boff = (((wn * 64 + (lane & 15)) * 32 + (lane >> 4) * 8)) ^ ((lane & 7) << 3);

  STAGE(0, 0); STAGE(1, 1);   // 8 loads in flight

  int cur = 0, sb = 2;
  for (int t = 0; t < NK; ++t) {
    if (t + 1 < NK) { asm volatile("s_waitcnt vmcnt(4)" ::: "memory"); }
    else            { asm volatile("s_waitcnt vmcnt(0)" ::: "memory"); }
    __builtin_amdgcn_s_barrier();
    if (t + 2 < NK) STAGE(sb, t + 2);
    bf16x8 af[8], bv8[4];
#pragma unroll
    for (int mf = 0; mf < 8; ++mf) af[mf] = *(const bf16x8*)&As[cur][aoff + mf * 512];
#pragma unroll
    for (int nf = 0; nf < 4; ++nf) bv8[nf] = *(const bf16x8*)&Bs[cur][boff + nf * 512];
    __builtin_amdgcn_s_setprio(1);
#pragma unroll
    for (int mf = 0; mf < 8; ++mf)
#pragma unroll
      for (int nf = 0; nf < 4; ++nf)
        acc[mf][nf] = __builtin_amdgcn_mfma_f32_16x16x32_bf16(af[mf], bv8[nf], acc[mf][nf], 0, 0, 0);
    __builtin_amdgcn_s_setprio(0);
    __builtin_amdgcn_sched_barrier(0);   // pin reads+uses above next barrier (rule #18)
    cur = (cur == 2) ? 0 : cur + 1;
    sb  = (sb  == 2) ? 0 : sb  + 1;
  }

  // epilogue
  int rb = wm * 128 + (lane >> 4) * 4;
  int cb = n0 + wn * 64 + (lane & 15);
  if (MODE) {
#pragma unroll
    for (int mf = 0; mf < 8; ++mf) {
#pragma unroll
      for (int j = 0; j < 4; ++j) {
        int gi = m0 + rb + mf * 16 + j;
        if (gi < ne) {
          int p = seg + gi;
          int tok = token_id[p];
          float wt = weightv[p];
          float* orow = yout + (size_t)tok * D_DIM + cb;
#pragma unroll
          for (int nf = 0; nf < 4; ++nf)
            atomicAdd(&orow[nf * 16], wt * acc[mf][nf][j]);
        }
      }
    }
  } else {
    const float* be = bias + (size_t)e * H_DIM + cb;
    float bvv[4];
#pragma unroll
    for (int nf = 0; nf < 4; ++nf) bvv[nf] = be[nf * 16];
#pragma unroll
    for (int mf = 0; mf < 8; ++mf) {
#pragma unroll
      for (int j = 0; j < 4; ++j) {
        int gi = m0 + rb + mf * 16 + j;
        if (gi < ne) {
          unsigned short* hrow = hout + (size_t)(seg + gi) * H_DIM + cb;
#pragma unroll
          for (int nf = 0; nf < 4; ++nf)
            hrow[nf * 16] = f2b(gelu_tanh(acc[mf][nf][j] + bvv[nf]));
        }
      }
    }
  }
}

extern "C" void kernel_launch(void* const* d_in, const int* in_sizes, int n_in,
                              void* d_out, int out_size, void* d_ws, size_t ws_size,
                              hipStream_t stream) {
  const float* x      = (const float*)d_in[0];
  const float* gate_w = (const float*)d_in[1];
  const float* gate_b = (const float*)d_in[2];
  const float* w1     = (const float*)d_in[3];
  const float* b1     = (const float*)d_in[4];
  const float* w2     = (const float*)d_in[5];
  const float* b2     = (const float*)d_in[6];
  float* out = (float*)d_out;

  uint8_t* ws = (uint8_t*)d_ws;
  unsigned short* hbuf = (unsigned short*)(ws);                 // 128 MiB
  unsigned short* xb   = (unsigned short*)(ws + 134217728ull);  // 16 MiB
  unsigned short* w1t  = (unsigned short*)(ws + 150994944ull);  // 64 MiB
  unsigned short* w2t  = (unsigned short*)(ws + 218103808ull);  // 64 MiB
  int*    token_id = (int*)  (ws + 285212672ull);               // 64 KiB
  float*  weightv  = (float*)(ws + 285278208ull);               // 64 KiB
  float2* wts      = (float2*)(ws + 285343744ull);              // 64 KiB
  int2*   sel      = (int2*) (ws + 285409280ull);               // 64 KiB
  int*    meta     = (int*)  (ws + 285474816ull);               // 512 B
  int2*   wl       = (int2*) (ws + 285475328ull);               // 2 KiB

  hipMemsetAsync(meta, 0, 512, stream);

  moe_gate_conv<<<dim3(T_TOK / 4), 256, 0, stream>>>(x, gate_w, gate_b, xb, sel, wts, meta);
  moe_transpose<<<dim3(H_DIM / 64, D_DIM / 64, E_NUM), 256, 0, stream>>>(w1, w1t, D_DIM, H_DIM);
  moe_transpose<<<dim3(D_DIM / 64, H_DIM / 64, E_NUM), 256, 0, stream>>>(w2, w2t, H_DIM, D_DIM);
  moe_scan<<<1, 64, 0, stream>>>(meta, wl);
  moe_scatter<<<dim3(T_TOK / 256), 256, 0, stream>>>(sel, wts, meta, token_id, weightv);
  moe_outinit<<<dim3(T_TOK), 256, 0, stream>>>(sel, wts, b2, out);

  moe_gemm_pipe<0><<<dim3(H_DIM / 256, WL_MAX), 512, 0, stream>>>(
      xb, w1t, b1, meta, wl, token_id, weightv, hbuf, nullptr);

  moe_gemm_pipe<1><<<dim3((D_DIM / 256) * 2, WL_MAX), 512, 0, stream>>>(
      hbuf, w2t, nullptr, meta, wl, token_id, weightv, nullptr, out);
}

// Round 6
// 889.294 us; speedup vs baseline: 1.0926x; 1.0926x over previous
//
#include <hip/hip_runtime.h>
#include <hip/hip_bf16.h>
#include <stdint.h>

#define T_TOK 8192
#define D_DIM 1024
#define E_NUM 8
#define H_DIM 4096
#define NPAD 144          // padded wl count, multiple of 8 (wl max = 135)
#define PPX (NPAD / 8)    // panels per XCD = 18

typedef short bf16x8 __attribute__((ext_vector_type(8)));
typedef float f32x4 __attribute__((ext_vector_type(4)));

#define AS1 __attribute__((address_space(1)))
#define AS3 __attribute__((address_space(3)))

__device__ __forceinline__ unsigned short f2b(float f) {
  union { float f; uint32_t u; } v; v.f = f;
  uint32_t r = (v.u + 0x7fffu + ((v.u >> 16) & 1u)) >> 16;
  return (unsigned short)r;
}

__device__ __forceinline__ float gelu_tanh(float x) {
  float u = 0.7978845608028654f * (x + 0.044715f * x * x * x);
  u = fminf(fmaxf(u, -15.f), 15.f);
  float e = __expf(2.f * u);
  float t = (e - 1.f) / (e + 1.f);
  return 0.5f * x * (1.f + t);
}

__device__ __forceinline__ void gload_lds16(const void* g, void* l) {
  __builtin_amdgcn_global_load_lds((const AS1 uint32_t*)g, (AS3 uint32_t*)l, 16, 0, 0);
}

// ---------------- gate + x->bf16 conversion fused ----------------
__global__ __launch_bounds__(256) void moe_gate_conv(const float* __restrict__ x,
                                                     const float* __restrict__ gw,
                                                     const float* __restrict__ gb,
                                                     unsigned short* __restrict__ xb,
                                                     int2* __restrict__ sel,
                                                     float2* __restrict__ wts,
                                                     int* __restrict__ meta) {
  int lane = threadIdx.x & 63;
  int t = blockIdx.x * 4 + (threadIdx.x >> 6);
  const float* xr = x + (size_t)t * D_DIM;
  unsigned short* xo = xb + (size_t)t * D_DIM;
  float acc[8];
#pragma unroll
  for (int e = 0; e < 8; e++) acc[e] = 0.f;
#pragma unroll
  for (int i = 0; i < 4; i++) {
    int d0 = lane * 4 + i * 256;
    float4 xv = *(const float4*)(xr + d0);
    ushort4 o;
    o.x = f2b(xv.x); o.y = f2b(xv.y); o.z = f2b(xv.z); o.w = f2b(xv.w);
    *(ushort4*)(xo + d0) = o;
    const float* gp = gw + (size_t)d0 * 8;
    float xs[4] = {xv.x, xv.y, xv.z, xv.w};
#pragma unroll
    for (int j = 0; j < 4; j++) {
#pragma unroll
      for (int e = 0; e < 8; e++) acc[e] += xs[j] * gp[j * 8 + e];
    }
  }
#pragma unroll
  for (int off = 32; off > 0; off >>= 1) {
#pragma unroll
    for (int e = 0; e < 8; e++) acc[e] += __shfl_xor(acc[e], off);
  }
  if (lane == 0) {
    float lg[8];
#pragma unroll
    for (int e = 0; e < 8; e++) lg[e] = acc[e] + gb[e];
    int e0 = 0; float b0 = lg[0];
#pragma unroll
    for (int e = 1; e < 8; e++) if (lg[e] > b0) { b0 = lg[e]; e0 = e; }
    int e1 = -1; float b1v = -1e30f;
#pragma unroll
    for (int e = 0; e < 8; e++) if (e != e0 && lg[e] > b1v) { b1v = lg[e]; e1 = e; }
    float d = __expf(b1v - b0);
    float w0 = 1.f / (1.f + d), w1 = d / (1.f + d);
    sel[t] = make_int2(e0, e1);
    wts[t] = make_float2(w0, w1);
    atomicAdd(&meta[e0], 1);
    atomicAdd(&meta[e1], 1);
  }
}

// ---------------- transpose + convert: in [E][R][C] f32 -> out [E][C][R] bf16 ----------------
__global__ __launch_bounds__(256) void moe_transpose(const float* __restrict__ in,
                                                     unsigned short* __restrict__ out,
                                                     int R, int C) {
  int e = blockIdx.z;
  int c0 = blockIdx.x * 64, r0 = blockIdx.y * 64;
  __shared__ float tile[64][65];
  const float* ine = in + (size_t)e * R * C;
  unsigned short* oute = out + (size_t)e * R * C;
  int tr = threadIdx.x >> 2;
  int tc4 = (threadIdx.x & 3) * 16;
#pragma unroll
  for (int p = 0; p < 4; p++) {
    int c = tc4 + p * 4;
    float4 v = *(const float4*)(ine + (size_t)(r0 + tr) * C + c0 + c);
    tile[tr][c] = v.x; tile[tr][c + 1] = v.y; tile[tr][c + 2] = v.z; tile[tr][c + 3] = v.w;
  }
  __syncthreads();
#pragma unroll
  for (int p = 0; p < 4; p++) {
    int rr = tc4 + p * 4;
    ushort4 o;
    o.x = f2b(tile[rr + 0][tr]);
    o.y = f2b(tile[rr + 1][tr]);
    o.z = f2b(tile[rr + 2][tr]);
    o.w = f2b(tile[rr + 3][tr]);
    *(ushort4*)(oute + (size_t)(c0 + tr) * R + r0 + rr) = o;
  }
}

// meta layout: [0..7] counts, [8..16] offsets(+total), [17] wl_count, [20..27] cursor
__global__ void moe_scan(int* meta, int2* wl) {
  if (threadIdx.x == 0 && blockIdx.x == 0) {
    int o = 0;
    for (int e = 0; e < 8; e++) { meta[8 + e] = o; meta[20 + e] = o; o += meta[e]; }
    meta[16] = o;
    int w = 0;
    for (int e = 0; e < 8; e++)
      for (int m0 = 0; m0 < meta[e]; m0 += 128) wl[w++] = make_int2(e, m0);
    meta[17] = w;
  }
}

__global__ __launch_bounds__(256) void moe_scatter(const int2* __restrict__ sel,
                                                   const float2* __restrict__ wts,
                                                   int* __restrict__ meta,
                                                   int* __restrict__ token_id,
                                                   float* __restrict__ weightv) {
  int t = blockIdx.x * 256 + threadIdx.x;
  if (t >= T_TOK) return;
  int2 s = sel[t];
  float2 w = wts[t];
  int p0 = atomicAdd(&meta[20 + s.x], 1); token_id[p0] = t; weightv[p0] = w.x;
  int p1 = atomicAdd(&meta[20 + s.y], 1); token_id[p1] = t; weightv[p1] = w.y;
}

// ---------------- out init: out[t] = w0*b2[e0] + w1*b2[e1] ----------------
__global__ __launch_bounds__(256) void moe_outinit(const int2* __restrict__ sel,
                                                   const float2* __restrict__ wts,
                                                   const float* __restrict__ b2,
                                                   float* __restrict__ out) {
  int t = blockIdx.x;
  int d = threadIdx.x * 4;
  int2 s = sel[t];
  float2 w = wts[t];
  float4 a = *(const float4*)(b2 + (size_t)s.x * D_DIM + d);
  float4 b = *(const float4*)(b2 + (size_t)s.y * D_DIM + d);
  float4 o;
  o.x = w.x * a.x + w.y * b.x;
  o.y = w.x * a.y + w.y * b.y;
  o.z = w.x * a.z + w.y * b.z;
  o.w = w.x * a.w + w.y * b.w;
  *(float4*)(out + (size_t)t * D_DIM + d) = o;
}

// ---------------- GEMM1: h[p,:] = gelu(x[tok[p]] @ w1[e] + b1[e]), bf16 out ----------------
// Block decode (XCD-chunked): xcd = b&7 owns panels [xcd*PPX, xcd*PPX+PPX); within an
// XCD all NB n-blocks of a panel are consecutive -> A-panel fetched once per XCD L2.
__global__ __launch_bounds__(256) void moe_gemm1(const unsigned short* __restrict__ xb,
                                                 const unsigned short* __restrict__ w1t,
                                                 const float* __restrict__ b1,
                                                 const int* __restrict__ meta,
                                                 const int2* __restrict__ wl,
                                                 const int* __restrict__ token_id,
                                                 unsigned short* __restrict__ hbuf) {
  int b = blockIdx.x;
  int c = b & 7, u = b >> 3;
  int n = u & 31, ps = u >> 5;           // NB = 32
  int wi = c * PPX + ps;
  if (wi >= meta[17]) return;
  int e = wl[wi].x, m0 = wl[wi].y;
  int seg = meta[8 + e], ne = meta[9 + e] - seg;
  int n0 = n * 128;
  const unsigned short* wB = w1t + (size_t)e * H_DIM * D_DIM;  // [H][D] bf16

  __shared__ unsigned short As[2][4096];
  __shared__ unsigned short Bs[2][4096];

  int tid = threadIdx.x, lane = tid & 63, wv = tid >> 6;
  const unsigned short* aptr[2];
  const unsigned short* bptr[2];
#pragma unroll
  for (int q = 0; q < 2; q++) {
    int chunk = (wv + 4 * q) * 64 + lane;
    int row = chunk >> 2;
    int ko = (chunk & 3) * 8;
    int gi = m0 + row; if (gi >= ne) gi = m0;
    int tok = token_id[seg + gi];
    aptr[q] = xb + (size_t)tok * D_DIM + ko;
    bptr[q] = wB + (size_t)(n0 + row) * D_DIM + ko;
  }
  auto stage = [&](int buf, int kt) {
#pragma unroll
    for (int q = 0; q < 2; q++) {
      gload_lds16(aptr[q] + kt * 32, &As[buf][(wv + 4 * q) * 512]);
      gload_lds16(bptr[q] + kt * 32, &Bs[buf][(wv + 4 * q) * 512]);
    }
  };

  f32x4 acc[4][4] = {};
  int wr = wv >> 1, wc = wv & 1;
  int abase = (wr * 64 + (lane & 15)) * 32 + (lane >> 4) * 8;
  int bbase = (wc * 64 + (lane & 15)) * 32 + (lane >> 4) * 8;

  stage(0, 0);
  __syncthreads();
  const int nk = D_DIM / 32;
  for (int kt = 0; kt < nk; ++kt) {
    int cur = kt & 1;
    if (kt + 1 < nk) stage(cur ^ 1, kt + 1);
    bf16x8 af[4], bfr[4];
#pragma unroll
    for (int m = 0; m < 4; m++) af[m] = *(const bf16x8*)&As[cur][abase + m * 512];
#pragma unroll
    for (int nn = 0; nn < 4; nn++) bfr[nn] = *(const bf16x8*)&Bs[cur][bbase + nn * 512];
#pragma unroll
    for (int m = 0; m < 4; m++)
#pragma unroll
      for (int nn = 0; nn < 4; nn++)
        acc[m][nn] = __builtin_amdgcn_mfma_f32_16x16x32_bf16(af[m], bfr[nn], acc[m][nn], 0, 0, 0);
    __syncthreads();
  }

  int rbase = wr * 64 + (lane >> 4) * 4;
  int cbase = n0 + wc * 64 + (lane & 15);
  const float* b1e = b1 + (size_t)e * H_DIM + cbase;
  float bv[4];
#pragma unroll
  for (int nn = 0; nn < 4; nn++) bv[nn] = b1e[nn * 16];
#pragma unroll
  for (int m = 0; m < 4; m++) {
#pragma unroll
    for (int j = 0; j < 4; j++) {
      int gi = m0 + rbase + m * 16 + j;
      if (gi < ne) {
        unsigned short* hrow = hbuf + (size_t)(seg + gi) * H_DIM + cbase;
#pragma unroll
        for (int nn = 0; nn < 4; nn++) {
          float v = acc[m][nn][j] + bv[nn];
          hrow[nn * 16] = f2b(gelu_tanh(v));
        }
      }
    }
  }
}

// ---------------- GEMM2: out[tok[p],:] += w_p * (h[p,:] @ w2[e]) (bias via outinit) ----------
__global__ __launch_bounds__(256) void moe_gemm2(const unsigned short* __restrict__ hbuf,
                                                 const unsigned short* __restrict__ w2t,
                                                 const int* __restrict__ meta,
                                                 const int2* __restrict__ wl,
                                                 const int* __restrict__ token_id,
                                                 const float* __restrict__ weightv,
                                                 float* __restrict__ out) {
  int b = blockIdx.x;
  int c = b & 7, u = b >> 3;
  int n = u & 7, ps = u >> 3;            // NB = 8
  int wi = c * PPX + ps;
  if (wi >= meta[17]) return;
  int e = wl[wi].x, m0 = wl[wi].y;
  int seg = meta[8 + e], ne = meta[9 + e] - seg;
  int n0 = n * 128;
  const unsigned short* wB = w2t + (size_t)e * D_DIM * H_DIM;  // [D][H] bf16

  __shared__ unsigned short As[2][4096];
  __shared__ unsigned short Bs[2][4096];

  int tid = threadIdx.x, lane = tid & 63, wv = tid >> 6;
  const unsigned short* aptr[2];
  const unsigned short* bptr[2];
#pragma unroll
  for (int q = 0; q < 2; q++) {
    int chunk = (wv + 4 * q) * 64 + lane;
    int row = chunk >> 2;
    int ko = (chunk & 3) * 8;
    int gi = m0 + row; if (gi >= ne) gi = m0;
    aptr[q] = hbuf + (size_t)(seg + gi) * H_DIM + ko;
    bptr[q] = wB + (size_t)(n0 + row) * H_DIM + ko;
  }
  auto stage = [&](int buf, int kt) {
#pragma unroll
    for (int q = 0; q < 2; q++) {
      gload_lds16(aptr[q] + kt * 32, &As[buf][(wv + 4 * q) * 512]);
      gload_lds16(bptr[q] + kt * 32, &Bs[buf][(wv + 4 * q) * 512]);
    }
  };

  f32x4 acc[4][4] = {};
  int wr = wv >> 1, wc = wv & 1;
  int abase = (wr * 64 + (lane & 15)) * 32 + (lane >> 4) * 8;
  int bbase = (wc * 64 + (lane & 15)) * 32 + (lane >> 4) * 8;

  stage(0, 0);
  __syncthreads();
  const int nk = H_DIM / 32;
  for (int kt = 0; kt < nk; ++kt) {
    int cur = kt & 1;
    if (kt + 1 < nk) stage(cur ^ 1, kt + 1);
    bf16x8 af[4], bfr[4];
#pragma unroll
    for (int m = 0; m < 4; m++) af[m] = *(const bf16x8*)&As[cur][abase + m * 512];
#pragma unroll
    for (int nn = 0; nn < 4; nn++) bfr[nn] = *(const bf16x8*)&Bs[cur][bbase + nn * 512];
#pragma unroll
    for (int m = 0; m < 4; m++)
#pragma unroll
      for (int nn = 0; nn < 4; nn++)
        acc[m][nn] = __builtin_amdgcn_mfma_f32_16x16x32_bf16(af[m], bfr[nn], acc[m][nn], 0, 0, 0);
    __syncthreads();
  }

  int rbase = wr * 64 + (lane >> 4) * 4;
  int cbase = n0 + wc * 64 + (lane & 15);
#pragma unroll
  for (int m = 0; m < 4; m++) {
#pragma unroll
    for (int j = 0; j < 4; j++) {
      int gi = m0 + rbase + m * 16 + j;
      if (gi < ne) {
        int p = seg + gi;
        int tok = token_id[p];
        float wt = weightv[p];
        float* orow = out + (size_t)tok * D_DIM + cbase;
#pragma unroll
        for (int nn = 0; nn < 4; nn++)
          atomicAdd(&orow[nn * 16], wt * acc[m][nn][j]);
      }
    }
  }
}

extern "C" void kernel_launch(void* const* d_in, const int* in_sizes, int n_in,
                              void* d_out, int out_size, void* d_ws, size_t ws_size,
                              hipStream_t stream) {
  const float* x      = (const float*)d_in[0];
  const float* gate_w = (const float*)d_in[1];
  const float* gate_b = (const float*)d_in[2];
  const float* w1     = (const float*)d_in[3];
  const float* b1     = (const float*)d_in[4];
  const float* w2     = (const float*)d_in[5];
  const float* b2     = (const float*)d_in[6];
  float* out = (float*)d_out;

  uint8_t* ws = (uint8_t*)d_ws;
  unsigned short* hbuf = (unsigned short*)(ws);                 // 128 MiB
  unsigned short* xb   = (unsigned short*)(ws + 134217728ull);  // 16 MiB
  unsigned short* w1t  = (unsigned short*)(ws + 150994944ull);  // 64 MiB
  unsigned short* w2t  = (unsigned short*)(ws + 218103808ull);  // 64 MiB
  int*    token_id = (int*)  (ws + 285212672ull);               // 64 KiB
  float*  weightv  = (float*)(ws + 285278208ull);               // 64 KiB
  float2* wts      = (float2*)(ws + 285343744ull);              // 64 KiB
  int2*   sel      = (int2*) (ws + 285409280ull);               // 64 KiB
  int*    meta     = (int*)  (ws + 285474816ull);               // 512 B
  int2*   wl       = (int2*) (ws + 285475328ull);               // 2 KiB

  hipMemsetAsync(meta, 0, 512, stream);

  moe_gate_conv<<<dim3(T_TOK / 4), 256, 0, stream>>>(x, gate_w, gate_b, xb, sel, wts, meta);
  moe_transpose<<<dim3(H_DIM / 64, D_DIM / 64, E_NUM), 256, 0, stream>>>(w1, w1t, D_DIM, H_DIM);
  moe_transpose<<<dim3(D_DIM / 64, H_DIM / 64, E_NUM), 256, 0, stream>>>(w2, w2t, H_DIM, D_DIM);
  moe_scan<<<1, 64, 0, stream>>>(meta, wl);
  moe_scatter<<<dim3(T_TOK / 256), 256, 0, stream>>>(sel, wts, meta, token_id, weightv);
  moe_outinit<<<dim3(T_TOK), 256, 0, stream>>>(sel, wts, b2, out);

  moe_gemm1<<<dim3(NPAD * 32), 256, 0, stream>>>(xb, w1t, b1, meta, wl, token_id, hbuf);
  moe_gemm2<<<dim3(NPAD * 8), 256, 0, stream>>>(hbuf, w2t, meta, wl, token_id, weightv, out);
}